// Round 1
// baseline (8607.992 us; speedup 1.0000x reference)
//
#include <hip/hip_runtime.h>
#include <math.h>

#define B_   64
#define N_   197
#define C_   768
#define H_   12
#define D_   64
#define BN   12608      // B_*N_
#define O3   2304       // 3*C_
#define QKV_ELEMS 9682944   // B_*H_*N_*D_ = BN*C_
#define SCALE 0.125f    // D^-0.5

// ---------------------------------------------------------------------------
// Kernel 1: QKV projection GEMM.  Y[m,o] = sum_k x[m,k] * w[o,k] + bias[o]
// 128x128 tile, BK=16, 8x8 micro-tile per thread (256 threads).
// Epilogue scatters into Q/K/V with layout (B,H,N,D); Q gets *SCALE.
// ---------------------------------------------------------------------------
__global__ __launch_bounds__(256) void qkv_gemm(
    const float* __restrict__ x,      // [BN, 768]
    const float* __restrict__ w,      // [2304, 768]
    const float* __restrict__ qb,
    const float* __restrict__ kb,
    const float* __restrict__ vb,
    float* __restrict__ qkv)          // ws: 3 x [B,H,N,D]
{
    __shared__ float As[16][132];     // [k][m], pad to 132
    __shared__ float Bs[16][132];     // [k][o]
    const int bo = blockIdx.x;        // 0..17
    const int bm = blockIdx.y;        // 0..98
    const int t  = threadIdx.x;
    const int tx = t & 15, ty = t >> 4;
    const int m0 = bm * 128, o0 = bo * 128;

    float acc[8][8];
#pragma unroll
    for (int i = 0; i < 8; ++i)
#pragma unroll
        for (int j = 0; j < 8; ++j) acc[i][j] = 0.f;

    const int lm = t >> 1;            // 0..127 row within tile
    const int lp = t & 1;             // k-half: 0 or 8

    for (int kt = 0; kt < 48; ++kt) {
        const int k0 = kt * 16;
        // ---- stage A (transposed to [k][m]) ----
        {
            const int gm = m0 + lm;
            float4 v0, v1;
            if (gm < BN) {
                const float* p = x + (size_t)gm * 768 + k0 + lp * 8;
                v0 = *(const float4*)(p);
                v1 = *(const float4*)(p + 4);
            } else {
                v0 = make_float4(0.f,0.f,0.f,0.f); v1 = v0;
            }
            const int kk = lp * 8;
            As[kk+0][lm] = v0.x; As[kk+1][lm] = v0.y;
            As[kk+2][lm] = v0.z; As[kk+3][lm] = v0.w;
            As[kk+4][lm] = v1.x; As[kk+5][lm] = v1.y;
            As[kk+6][lm] = v1.z; As[kk+7][lm] = v1.w;
        }
        // ---- stage B ----
        {
            const int go = o0 + lm;   // always < 2304
            const float* p = w + (size_t)go * 768 + k0 + lp * 8;
            float4 v0 = *(const float4*)(p);
            float4 v1 = *(const float4*)(p + 4);
            const int kk = lp * 8;
            Bs[kk+0][lm] = v0.x; Bs[kk+1][lm] = v0.y;
            Bs[kk+2][lm] = v0.z; Bs[kk+3][lm] = v0.w;
            Bs[kk+4][lm] = v1.x; Bs[kk+5][lm] = v1.y;
            Bs[kk+6][lm] = v1.z; Bs[kk+7][lm] = v1.w;
        }
        __syncthreads();
#pragma unroll
        for (int k = 0; k < 16; ++k) {
            float a[8], b[8];
            *(float4*)(a)     = *(const float4*)&As[k][ty*8];
            *(float4*)(a + 4) = *(const float4*)&As[k][ty*8 + 4];
            *(float4*)(b)     = *(const float4*)&Bs[k][tx*8];
            *(float4*)(b + 4) = *(const float4*)&Bs[k][tx*8 + 4];
#pragma unroll
            for (int i = 0; i < 8; ++i)
#pragma unroll
                for (int j = 0; j < 8; ++j)
                    acc[i][j] = fmaf(a[i], b[j], acc[i][j]);
        }
        __syncthreads();
    }

    // ---- epilogue: bias + scatter to (B,H,N,D) ----
    const int which = o0 / 768;                 // tile lies fully in one of q/k/v
    const float* bias = (which == 0) ? qb : ((which == 1) ? kb : vb);
    float* dst = qkv + (size_t)which * QKV_ELEMS;
    const float sc = (which == 0) ? SCALE : 1.0f;

#pragma unroll
    for (int i = 0; i < 8; ++i) {
        const int gm = m0 + ty*8 + i;
        if (gm >= BN) break;
        const int b = gm / 197, n = gm % 197;
#pragma unroll
        for (int j = 0; j < 8; ++j) {
            const int ol = (o0 + tx*8 + j) % 768;
            const int h = ol >> 6, d = ol & 63;
            dst[(((size_t)b*12 + h)*197 + n)*64 + d] = (acc[i][j] + bias[ol]) * sc;
        }
    }
}

// ---------------------------------------------------------------------------
// Kernel 2: fused attention per (b,h).  One block = 64 Q-rows of one (b,h).
// Flash-style online softmax over 4 column chunks of 64 keys.
// Relative-position-bias index computed inline (static 14x14+cls formula).
// ---------------------------------------------------------------------------
__global__ __launch_bounds__(256) void attn_kernel(
    const float* __restrict__ qkv,        // ws base (Q,K,V)
    const float* __restrict__ rel_table,  // [732, 12]
    float* __restrict__ aout)             // [BN, 768]  (b,n,h*64+d)
{
    __shared__ float Qs[64][68];   // [d][r]
    __shared__ float KV[64][68];   // K: [d][c]; later V: [c][d]
    __shared__ float P [64][68];   // [c][r]

    const int rt = blockIdx.x;     // 0..3 row tile
    const int bh = blockIdx.y;     // 0..767
    const int h  = bh % 12;
    const int bb = bh / 12;
    const size_t base = (size_t)bh * (197*64);
    const float* Q = qkv + base;
    const float* K = qkv + (size_t)QKV_ELEMS + base;
    const float* V = qkv + (size_t)2*QKV_ELEMS + base;
    const int t = threadIdx.x, tx = t & 15, ty = t >> 4;
    const int r0 = rt * 64;

    // stage Q tile transposed: Qs[d][r]
    {
        const int r = t >> 2, q = t & 3;
        const int n = r0 + r;
#pragma unroll
        for (int j = 0; j < 4; ++j) {
            const int d0 = q*16 + j*4;
            float4 v = (n < 197) ? *(const float4*)(Q + n*64 + d0)
                                 : make_float4(0.f,0.f,0.f,0.f);
            Qs[d0+0][r] = v.x; Qs[d0+1][r] = v.y;
            Qs[d0+2][r] = v.z; Qs[d0+3][r] = v.w;
        }
    }

    float m_run[4], l_run[4], accO[4][4];
#pragma unroll
    for (int i = 0; i < 4; ++i) {
        m_run[i] = -INFINITY; l_run[i] = 0.f;
#pragma unroll
        for (int j = 0; j < 4; ++j) accO[i][j] = 0.f;
    }

    for (int cc = 0; cc < 4; ++cc) {
        // ---- stage K chunk transposed: KV[d][c] ----
        {
            const int c = t >> 2, q = t & 3;
            const int mg = cc*64 + c;
#pragma unroll
            for (int j = 0; j < 4; ++j) {
                const int d0 = q*16 + j*4;
                float4 v = (mg < 197) ? *(const float4*)(K + mg*64 + d0)
                                      : make_float4(0.f,0.f,0.f,0.f);
                KV[d0+0][c] = v.x; KV[d0+1][c] = v.y;
                KV[d0+2][c] = v.z; KV[d0+3][c] = v.w;
            }
        }
        __syncthreads();

        // ---- S chunk = Q K^T  (rows 4ty.., cols 4tx..) ----
        float s[4][4];
#pragma unroll
        for (int i = 0; i < 4; ++i)
#pragma unroll
            for (int j = 0; j < 4; ++j) s[i][j] = 0.f;
#pragma unroll
        for (int d = 0; d < 64; ++d) {
            float a[4], b[4];
            *(float4*)a = *(const float4*)&Qs[d][ty*4];
            *(float4*)b = *(const float4*)&KV[d][tx*4];
#pragma unroll
            for (int i = 0; i < 4; ++i)
#pragma unroll
                for (int j = 0; j < 4; ++j)
                    s[i][j] = fmaf(a[i], b[j], s[i][j]);
        }

        // ---- add relative position bias, mask invalid cols ----
#pragma unroll
        for (int j = 0; j < 4; ++j) {
            const int mg = cc*64 + tx*4 + j;
            if (mg >= 197) {
#pragma unroll
                for (int i = 0; i < 4; ++i) s[i][j] = -1e30f;
            } else {
#pragma unroll
                for (int i = 0; i < 4; ++i) {
                    const int nr = r0 + ty*4 + i;
                    const int n = (nr < 197) ? nr : 0;  // rows >=197 never stored
                    int idx;
                    if (n == 0 && mg == 0)      idx = 731;
                    else if (n == 0)            idx = 729;
                    else if (mg == 0)           idx = 730;
                    else {
                        const int p = n - 1, q2 = mg - 1;
                        const int dr = (p / 14 - q2 / 14) + 13;
                        const int dc = (p % 14 - q2 % 14) + 13;
                        idx = dr * 27 + dc;
                    }
                    s[i][j] += rel_table[idx * 12 + h];
                }
            }
        }

        // ---- online softmax (row-wise across the 16 tx lanes) ----
#pragma unroll
        for (int i = 0; i < 4; ++i) {
            float mx = fmaxf(fmaxf(s[i][0], s[i][1]), fmaxf(s[i][2], s[i][3]));
#pragma unroll
            for (int off = 1; off < 16; off <<= 1)
                mx = fmaxf(mx, __shfl_xor(mx, off));
            const float mnew = fmaxf(m_run[i], mx);
            const float alpha = __expf(m_run[i] - mnew);
            m_run[i] = mnew;
            float rs = 0.f;
#pragma unroll
            for (int j = 0; j < 4; ++j) {
                s[i][j] = __expf(s[i][j] - mnew);
                rs += s[i][j];
            }
#pragma unroll
            for (int off = 1; off < 16; off <<= 1)
                rs += __shfl_xor(rs, off);
            l_run[i] = l_run[i] * alpha + rs;
#pragma unroll
            for (int j = 0; j < 4; ++j) accO[i][j] *= alpha;
        }

        // ---- write P[c][r] ----
#pragma unroll
        for (int i = 0; i < 4; ++i)
#pragma unroll
            for (int j = 0; j < 4; ++j)
                P[tx*4 + j][ty*4 + i] = s[i][j];
        __syncthreads();

        // ---- stage V chunk: KV[c][d] (direct layout) ----
        {
            const int c = t >> 2, q = t & 3;
            const int mg = cc*64 + c;
#pragma unroll
            for (int j = 0; j < 4; ++j) {
                const int d0 = q*16 + j*4;
                float4 v = (mg < 197) ? *(const float4*)(V + mg*64 + d0)
                                      : make_float4(0.f,0.f,0.f,0.f);
                *(float4*)&KV[c][d0] = v;
            }
        }
        __syncthreads();

        // ---- O += P^T V  (rows 4ty.., d-cols 4tx..) ----
#pragma unroll
        for (int c = 0; c < 64; ++c) {
            float a[4], b[4];
            *(float4*)a = *(const float4*)&P[c][ty*4];
            *(float4*)b = *(const float4*)&KV[c][tx*4];
#pragma unroll
            for (int i = 0; i < 4; ++i)
#pragma unroll
                for (int j = 0; j < 4; ++j)
                    accO[i][j] = fmaf(a[i], b[j], accO[i][j]);
        }
        __syncthreads();
    }

    // ---- finalize: divide by l, store to (B,N,C) ----
#pragma unroll
    for (int i = 0; i < 4; ++i) {
        const int n = r0 + ty*4 + i;
        if (n < 197) {
            const float inv = 1.0f / l_run[i];
            float4 v = make_float4(accO[i][0]*inv, accO[i][1]*inv,
                                   accO[i][2]*inv, accO[i][3]*inv);
            *(float4*)(aout + ((size_t)(bb*197 + n))*768 + h*64 + tx*4) = v;
        }
    }
}

// ---------------------------------------------------------------------------
// Kernel 3: output projection GEMM.  out[m,o] = sum_k a[m,k]*w[o,k] + b[o]
// ---------------------------------------------------------------------------
__global__ __launch_bounds__(256) void proj_gemm(
    const float* __restrict__ a_in,   // [BN, 768]
    const float* __restrict__ w,      // [768, 768]
    const float* __restrict__ bias,   // [768]
    float* __restrict__ out)          // [BN, 768]
{
    __shared__ float As[16][132];
    __shared__ float Bs[16][132];
    const int bo = blockIdx.x;        // 0..5
    const int bm = blockIdx.y;        // 0..98
    const int t  = threadIdx.x;
    const int tx = t & 15, ty = t >> 4;
    const int m0 = bm * 128, o0 = bo * 128;

    float acc[8][8];
#pragma unroll
    for (int i = 0; i < 8; ++i)
#pragma unroll
        for (int j = 0; j < 8; ++j) acc[i][j] = 0.f;

    const int lm = t >> 1;
    const int lp = t & 1;

    for (int kt = 0; kt < 48; ++kt) {
        const int k0 = kt * 16;
        {
            const int gm = m0 + lm;
            float4 v0, v1;
            if (gm < BN) {
                const float* p = a_in + (size_t)gm * 768 + k0 + lp * 8;
                v0 = *(const float4*)(p);
                v1 = *(const float4*)(p + 4);
            } else {
                v0 = make_float4(0.f,0.f,0.f,0.f); v1 = v0;
            }
            const int kk = lp * 8;
            As[kk+0][lm] = v0.x; As[kk+1][lm] = v0.y;
            As[kk+2][lm] = v0.z; As[kk+3][lm] = v0.w;
            As[kk+4][lm] = v1.x; As[kk+5][lm] = v1.y;
            As[kk+6][lm] = v1.z; As[kk+7][lm] = v1.w;
        }
        {
            const int go = o0 + lm;   // < 768
            const float* p = w + (size_t)go * 768 + k0 + lp * 8;
            float4 v0 = *(const float4*)(p);
            float4 v1 = *(const float4*)(p + 4);
            const int kk = lp * 8;
            Bs[kk+0][lm] = v0.x; Bs[kk+1][lm] = v0.y;
            Bs[kk+2][lm] = v0.z; Bs[kk+3][lm] = v0.w;
            Bs[kk+4][lm] = v1.x; Bs[kk+5][lm] = v1.y;
            Bs[kk+6][lm] = v1.z; Bs[kk+7][lm] = v1.w;
        }
        __syncthreads();
#pragma unroll
        for (int k = 0; k < 16; ++k) {
            float a[8], b[8];
            *(float4*)(a)     = *(const float4*)&As[k][ty*8];
            *(float4*)(a + 4) = *(const float4*)&As[k][ty*8 + 4];
            *(float4*)(b)     = *(const float4*)&Bs[k][tx*8];
            *(float4*)(b + 4) = *(const float4*)&Bs[k][tx*8 + 4];
#pragma unroll
            for (int i = 0; i < 8; ++i)
#pragma unroll
                for (int j = 0; j < 8; ++j)
                    acc[i][j] = fmaf(a[i], b[j], acc[i][j]);
        }
        __syncthreads();
    }

#pragma unroll
    for (int i = 0; i < 8; ++i) {
        const int gm = m0 + ty*8 + i;
        if (gm >= BN) break;
        float* op = out + (size_t)gm * 768 + o0 + tx*8;
        float4 v0 = make_float4(acc[i][0] + bias[o0 + tx*8 + 0],
                                acc[i][1] + bias[o0 + tx*8 + 1],
                                acc[i][2] + bias[o0 + tx*8 + 2],
                                acc[i][3] + bias[o0 + tx*8 + 3]);
        float4 v1 = make_float4(acc[i][4] + bias[o0 + tx*8 + 4],
                                acc[i][5] + bias[o0 + tx*8 + 5],
                                acc[i][6] + bias[o0 + tx*8 + 6],
                                acc[i][7] + bias[o0 + tx*8 + 7]);
        *(float4*)(op)     = v0;
        *(float4*)(op + 4) = v1;
    }
}

// ---------------------------------------------------------------------------
extern "C" void kernel_launch(void* const* d_in, const int* in_sizes, int n_in,
                              void* d_out, int out_size, void* d_ws, size_t ws_size,
                              hipStream_t stream)
{
    const float* x         = (const float*)d_in[0];
    const float* qkv_w     = (const float*)d_in[1];
    const float* q_bias    = (const float*)d_in[2];
    const float* k_bias    = (const float*)d_in[3];
    const float* v_bias    = (const float*)d_in[4];
    const float* rel_table = (const float*)d_in[5];
    const float* proj_w    = (const float*)d_in[6];
    const float* proj_b    = (const float*)d_in[7];
    float* out = (float*)d_out;

    float* qkv  = (float*)d_ws;                       // 3 * QKV_ELEMS floats
    float* aout = (float*)d_ws + (size_t)3 * QKV_ELEMS; // QKV_ELEMS floats

    dim3 g1(18, 99);
    qkv_gemm<<<g1, 256, 0, stream>>>(x, qkv_w, q_bias, k_bias, v_bias, qkv);

    dim3 g2(4, 768);
    attn_kernel<<<g2, 256, 0, stream>>>(qkv, rel_table, aout);

    dim3 g3(6, 99);
    proj_gemm<<<g3, 256, 0, stream>>>(aout, proj_w, proj_b, out);
}

// Round 2
// 1054.371 us; speedup vs baseline: 8.1641x; 8.1641x over previous
//
#include <hip/hip_runtime.h>
#include <math.h>

#define B_   64
#define N_   197
#define C_   768
#define H_   12
#define D_   64
#define BN   12608      // B_*N_
#define O3   2304       // 3*C_
#define QKV_ELEMS 9682944   // B_*H_*N_*D_ = BN*C_
#define SCALE 0.125f    // D^-0.5

// ---------------------------------------------------------------------------
// Kernel 1: QKV projection GEMM.  Y[m,o] = sum_k x[m,k] * w[o,k] + bias[o]
// 128x128 tile, BK=16, 8x8 micro-tile per thread (256 threads).
// Epilogue scatters into Q/K/V with layout (B,H,N,D); Q gets *SCALE.
// ---------------------------------------------------------------------------
__global__ __launch_bounds__(256) void qkv_gemm(
    const float* __restrict__ x,      // [BN, 768]
    const float* __restrict__ w,      // [2304, 768]
    const float* __restrict__ qb,
    const float* __restrict__ kb,
    const float* __restrict__ vb,
    float* __restrict__ qkv)          // ws: 3 x [B,H,N,D]
{
    __shared__ float As[16][132];     // [k][m], pad to 132
    __shared__ float Bs[16][132];     // [k][o]
    const int bo = blockIdx.x;        // 0..17
    const int bm = blockIdx.y;        // 0..98
    const int t  = threadIdx.x;
    const int tx = t & 15, ty = t >> 4;
    const int m0 = bm * 128, o0 = bo * 128;

    float acc[8][8];
#pragma unroll
    for (int i = 0; i < 8; ++i)
#pragma unroll
        for (int j = 0; j < 8; ++j) acc[i][j] = 0.f;

    const int lm = t >> 1;            // 0..127 row within tile
    const int lp = t & 1;             // k-half: 0 or 8

    for (int kt = 0; kt < 48; ++kt) {
        const int k0 = kt * 16;
        // ---- stage A (transposed to [k][m]) ----
        {
            const int gm = m0 + lm;
            float4 v0, v1;
            if (gm < BN) {
                const float* p = x + (size_t)gm * 768 + k0 + lp * 8;
                v0 = *(const float4*)(p);
                v1 = *(const float4*)(p + 4);
            } else {
                v0 = make_float4(0.f,0.f,0.f,0.f); v1 = v0;
            }
            const int kk = lp * 8;
            As[kk+0][lm] = v0.x; As[kk+1][lm] = v0.y;
            As[kk+2][lm] = v0.z; As[kk+3][lm] = v0.w;
            As[kk+4][lm] = v1.x; As[kk+5][lm] = v1.y;
            As[kk+6][lm] = v1.z; As[kk+7][lm] = v1.w;
        }
        // ---- stage B ----
        {
            const int go = o0 + lm;   // always < 2304
            const float* p = w + (size_t)go * 768 + k0 + lp * 8;
            float4 v0 = *(const float4*)(p);
            float4 v1 = *(const float4*)(p + 4);
            const int kk = lp * 8;
            Bs[kk+0][lm] = v0.x; Bs[kk+1][lm] = v0.y;
            Bs[kk+2][lm] = v0.z; Bs[kk+3][lm] = v0.w;
            Bs[kk+4][lm] = v1.x; Bs[kk+5][lm] = v1.y;
            Bs[kk+6][lm] = v1.z; Bs[kk+7][lm] = v1.w;
        }
        __syncthreads();
#pragma unroll
        for (int k = 0; k < 16; ++k) {
            float a[8], b[8];
            *(float4*)(a)     = *(const float4*)&As[k][ty*8];
            *(float4*)(a + 4) = *(const float4*)&As[k][ty*8 + 4];
            *(float4*)(b)     = *(const float4*)&Bs[k][tx*8];
            *(float4*)(b + 4) = *(const float4*)&Bs[k][tx*8 + 4];
#pragma unroll
            for (int i = 0; i < 8; ++i)
#pragma unroll
                for (int j = 0; j < 8; ++j)
                    acc[i][j] = fmaf(a[i], b[j], acc[i][j]);
        }
        __syncthreads();
    }

    // ---- epilogue: bias + scatter to (B,H,N,D) ----
    const int which = o0 / 768;                 // tile lies fully in one of q/k/v
    const float* bias = (which == 0) ? qb : ((which == 1) ? kb : vb);
    float* dst = qkv + (size_t)which * QKV_ELEMS;
    const float sc = (which == 0) ? SCALE : 1.0f;

#pragma unroll
    for (int i = 0; i < 8; ++i) {
        const int gm = m0 + ty*8 + i;
        if (gm >= BN) break;
        const int b = gm / 197, n = gm % 197;
#pragma unroll
        for (int j = 0; j < 8; ++j) {
            const int ol = (o0 + tx*8 + j) % 768;
            const int h = ol >> 6, d = ol & 63;
            dst[(((size_t)b*12 + h)*197 + n)*64 + d] = (acc[i][j] + bias[ol]) * sc;
        }
    }
}

// ---------------------------------------------------------------------------
// Kernel 2: fused attention per (b,h).  One block = 64 Q-rows of one (b,h).
// Flash-style online softmax over 4 column chunks of 64 keys.
// R1 fix: cap unroll of the 64-iter FMA loops at 8 and force VGPR<=128
// (__launch_bounds__(256,4)) — R1's full unroll spilled to scratch
// (VGPR=256, 21.4 GB HBM traffic/dispatch, 7.6 ms).
// ---------------------------------------------------------------------------
__global__ __launch_bounds__(256, 4) void attn_kernel(
    const float* __restrict__ qkv,        // ws base (Q,K,V)
    const float* __restrict__ rel_table,  // [732, 12]
    float* __restrict__ aout)             // [BN, 768]  (b,n,h*64+d)
{
    __shared__ float Qs[64][68];   // [d][r]
    __shared__ float KV[64][68];   // K: [d][c]; later V: [c][d]
    __shared__ float P [64][68];   // [c][r]

    const int rt = blockIdx.x;     // 0..3 row tile
    const int bh = blockIdx.y;     // 0..767
    const int h  = bh % 12;
    const int bb = bh / 12;
    const size_t base = (size_t)bh * (197*64);
    const float* Q = qkv + base;
    const float* K = qkv + (size_t)QKV_ELEMS + base;
    const float* V = qkv + (size_t)2*QKV_ELEMS + base;
    const int t = threadIdx.x, tx = t & 15, ty = t >> 4;
    const int r0 = rt * 64;

    // stage Q tile transposed: Qs[d][r]
    {
        const int r = t >> 2, q = t & 3;
        const int n = r0 + r;
#pragma unroll
        for (int j = 0; j < 4; ++j) {
            const int d0 = q*16 + j*4;
            float4 v = (n < 197) ? *(const float4*)(Q + n*64 + d0)
                                 : make_float4(0.f,0.f,0.f,0.f);
            Qs[d0+0][r] = v.x; Qs[d0+1][r] = v.y;
            Qs[d0+2][r] = v.z; Qs[d0+3][r] = v.w;
        }
    }

    float m_run[4], l_run[4], accO[4][4];
#pragma unroll
    for (int i = 0; i < 4; ++i) {
        m_run[i] = -INFINITY; l_run[i] = 0.f;
#pragma unroll
        for (int j = 0; j < 4; ++j) accO[i][j] = 0.f;
    }

    for (int cc = 0; cc < 4; ++cc) {
        // ---- stage K chunk transposed: KV[d][c] ----
        {
            const int c = t >> 2, q = t & 3;
            const int mg = cc*64 + c;
#pragma unroll
            for (int j = 0; j < 4; ++j) {
                const int d0 = q*16 + j*4;
                float4 v = (mg < 197) ? *(const float4*)(K + mg*64 + d0)
                                      : make_float4(0.f,0.f,0.f,0.f);
                KV[d0+0][c] = v.x; KV[d0+1][c] = v.y;
                KV[d0+2][c] = v.z; KV[d0+3][c] = v.w;
            }
        }
        __syncthreads();

        // ---- S chunk = Q K^T  (rows 4ty.., cols 4tx..) ----
        float s[4][4];
#pragma unroll
        for (int i = 0; i < 4; ++i)
#pragma unroll
            for (int j = 0; j < 4; ++j) s[i][j] = 0.f;
#pragma unroll 8
        for (int d = 0; d < 64; ++d) {
            float a[4], b[4];
            *(float4*)a = *(const float4*)&Qs[d][ty*4];
            *(float4*)b = *(const float4*)&KV[d][tx*4];
#pragma unroll
            for (int i = 0; i < 4; ++i)
#pragma unroll
                for (int j = 0; j < 4; ++j)
                    s[i][j] = fmaf(a[i], b[j], s[i][j]);
        }

        // ---- add relative position bias, mask invalid cols ----
#pragma unroll
        for (int j = 0; j < 4; ++j) {
            const int mg = cc*64 + tx*4 + j;
            if (mg >= 197) {
#pragma unroll
                for (int i = 0; i < 4; ++i) s[i][j] = -1e30f;
            } else {
#pragma unroll
                for (int i = 0; i < 4; ++i) {
                    const int nr = r0 + ty*4 + i;
                    const int n = (nr < 197) ? nr : 0;  // rows >=197 never stored
                    int idx;
                    if (n == 0 && mg == 0)      idx = 731;
                    else if (n == 0)            idx = 729;
                    else if (mg == 0)           idx = 730;
                    else {
                        const int p = n - 1, q2 = mg - 1;
                        const int dr = (p / 14 - q2 / 14) + 13;
                        const int dc = (p % 14 - q2 % 14) + 13;
                        idx = dr * 27 + dc;
                    }
                    s[i][j] += rel_table[idx * 12 + h];
                }
            }
        }

        // ---- online softmax (row-wise across the 16 tx lanes) ----
#pragma unroll
        for (int i = 0; i < 4; ++i) {
            float mx = fmaxf(fmaxf(s[i][0], s[i][1]), fmaxf(s[i][2], s[i][3]));
#pragma unroll
            for (int off = 1; off < 16; off <<= 1)
                mx = fmaxf(mx, __shfl_xor(mx, off));
            const float mnew = fmaxf(m_run[i], mx);
            const float alpha = __expf(m_run[i] - mnew);
            m_run[i] = mnew;
            float rs = 0.f;
#pragma unroll
            for (int j = 0; j < 4; ++j) {
                s[i][j] = __expf(s[i][j] - mnew);
                rs += s[i][j];
            }
#pragma unroll
            for (int off = 1; off < 16; off <<= 1)
                rs += __shfl_xor(rs, off);
            l_run[i] = l_run[i] * alpha + rs;
#pragma unroll
            for (int j = 0; j < 4; ++j) accO[i][j] *= alpha;
        }

        // ---- write P[c][r] ----
#pragma unroll
        for (int i = 0; i < 4; ++i)
#pragma unroll
            for (int j = 0; j < 4; ++j)
                P[tx*4 + j][ty*4 + i] = s[i][j];
        __syncthreads();

        // ---- stage V chunk: KV[c][d] (direct layout) ----
        {
            const int c = t >> 2, q = t & 3;
            const int mg = cc*64 + c;
#pragma unroll
            for (int j = 0; j < 4; ++j) {
                const int d0 = q*16 + j*4;
                float4 v = (mg < 197) ? *(const float4*)(V + mg*64 + d0)
                                      : make_float4(0.f,0.f,0.f,0.f);
                *(float4*)&KV[c][d0] = v;
            }
        }
        __syncthreads();

        // ---- O += P^T V  (rows 4ty.., d-cols 4tx..) ----
#pragma unroll 8
        for (int c = 0; c < 64; ++c) {
            float a[4], b[4];
            *(float4*)a = *(const float4*)&P[c][ty*4];
            *(float4*)b = *(const float4*)&KV[c][tx*4];
#pragma unroll
            for (int i = 0; i < 4; ++i)
#pragma unroll
                for (int j = 0; j < 4; ++j)
                    accO[i][j] = fmaf(a[i], b[j], accO[i][j]);
        }
        __syncthreads();
    }

    // ---- finalize: divide by l, store to (B,N,C) ----
#pragma unroll
    for (int i = 0; i < 4; ++i) {
        const int n = r0 + ty*4 + i;
        if (n < 197) {
            const float inv = 1.0f / l_run[i];
            float4 v = make_float4(accO[i][0]*inv, accO[i][1]*inv,
                                   accO[i][2]*inv, accO[i][3]*inv);
            *(float4*)(aout + ((size_t)(bb*197 + n))*768 + h*64 + tx*4) = v;
        }
    }
}

// ---------------------------------------------------------------------------
// Kernel 3: output projection GEMM.  out[m,o] = sum_k a[m,k]*w[o,k] + b[o]
// ---------------------------------------------------------------------------
__global__ __launch_bounds__(256) void proj_gemm(
    const float* __restrict__ a_in,   // [BN, 768]
    const float* __restrict__ w,      // [768, 768]
    const float* __restrict__ bias,   // [768]
    float* __restrict__ out)          // [BN, 768]
{
    __shared__ float As[16][132];
    __shared__ float Bs[16][132];
    const int bo = blockIdx.x;        // 0..5
    const int bm = blockIdx.y;        // 0..98
    const int t  = threadIdx.x;
    const int tx = t & 15, ty = t >> 4;
    const int m0 = bm * 128, o0 = bo * 128;

    float acc[8][8];
#pragma unroll
    for (int i = 0; i < 8; ++i)
#pragma unroll
        for (int j = 0; j < 8; ++j) acc[i][j] = 0.f;

    const int lm = t >> 1;
    const int lp = t & 1;

    for (int kt = 0; kt < 48; ++kt) {
        const int k0 = kt * 16;
        {
            const int gm = m0 + lm;
            float4 v0, v1;
            if (gm < BN) {
                const float* p = a_in + (size_t)gm * 768 + k0 + lp * 8;
                v0 = *(const float4*)(p);
                v1 = *(const float4*)(p + 4);
            } else {
                v0 = make_float4(0.f,0.f,0.f,0.f); v1 = v0;
            }
            const int kk = lp * 8;
            As[kk+0][lm] = v0.x; As[kk+1][lm] = v0.y;
            As[kk+2][lm] = v0.z; As[kk+3][lm] = v0.w;
            As[kk+4][lm] = v1.x; As[kk+5][lm] = v1.y;
            As[kk+6][lm] = v1.z; As[kk+7][lm] = v1.w;
        }
        {
            const int go = o0 + lm;   // < 768
            const float* p = w + (size_t)go * 768 + k0 + lp * 8;
            float4 v0 = *(const float4*)(p);
            float4 v1 = *(const float4*)(p + 4);
            const int kk = lp * 8;
            Bs[kk+0][lm] = v0.x; Bs[kk+1][lm] = v0.y;
            Bs[kk+2][lm] = v0.z; Bs[kk+3][lm] = v0.w;
            Bs[kk+4][lm] = v1.x; Bs[kk+5][lm] = v1.y;
            Bs[kk+6][lm] = v1.z; Bs[kk+7][lm] = v1.w;
        }
        __syncthreads();
#pragma unroll
        for (int k = 0; k < 16; ++k) {
            float a[8], b[8];
            *(float4*)(a)     = *(const float4*)&As[k][ty*8];
            *(float4*)(a + 4) = *(const float4*)&As[k][ty*8 + 4];
            *(float4*)(b)     = *(const float4*)&Bs[k][tx*8];
            *(float4*)(b + 4) = *(const float4*)&Bs[k][tx*8 + 4];
#pragma unroll
            for (int i = 0; i < 8; ++i)
#pragma unroll
                for (int j = 0; j < 8; ++j)
                    acc[i][j] = fmaf(a[i], b[j], acc[i][j]);
        }
        __syncthreads();
    }

#pragma unroll
    for (int i = 0; i < 8; ++i) {
        const int gm = m0 + ty*8 + i;
        if (gm >= BN) break;
        float* op = out + (size_t)gm * 768 + o0 + tx*8;
        float4 v0 = make_float4(acc[i][0] + bias[o0 + tx*8 + 0],
                                acc[i][1] + bias[o0 + tx*8 + 1],
                                acc[i][2] + bias[o0 + tx*8 + 2],
                                acc[i][3] + bias[o0 + tx*8 + 3]);
        float4 v1 = make_float4(acc[i][4] + bias[o0 + tx*8 + 4],
                                acc[i][5] + bias[o0 + tx*8 + 5],
                                acc[i][6] + bias[o0 + tx*8 + 6],
                                acc[i][7] + bias[o0 + tx*8 + 7]);
        *(float4*)(op)     = v0;
        *(float4*)(op + 4) = v1;
    }
}

// ---------------------------------------------------------------------------
extern "C" void kernel_launch(void* const* d_in, const int* in_sizes, int n_in,
                              void* d_out, int out_size, void* d_ws, size_t ws_size,
                              hipStream_t stream)
{
    const float* x         = (const float*)d_in[0];
    const float* qkv_w     = (const float*)d_in[1];
    const float* q_bias    = (const float*)d_in[2];
    const float* k_bias    = (const float*)d_in[3];
    const float* v_bias    = (const float*)d_in[4];
    const float* rel_table = (const float*)d_in[5];
    const float* proj_w    = (const float*)d_in[6];
    const float* proj_b    = (const float*)d_in[7];
    float* out = (float*)d_out;

    float* qkv  = (float*)d_ws;                       // 3 * QKV_ELEMS floats
    float* aout = (float*)d_ws + (size_t)3 * QKV_ELEMS; // QKV_ELEMS floats

    dim3 g1(18, 99);
    qkv_gemm<<<g1, 256, 0, stream>>>(x, qkv_w, q_bias, k_bias, v_bias, qkv);

    dim3 g2(4, 768);
    attn_kernel<<<g2, 256, 0, stream>>>(qkv, rel_table, aout);

    dim3 g3(6, 99);
    proj_gemm<<<g3, 256, 0, stream>>>(aout, proj_w, proj_b, out);
}

// Round 3
// 426.585 us; speedup vs baseline: 20.1788x; 2.4717x over previous
//
#include <hip/hip_runtime.h>
#include <math.h>

#define B_   64
#define N_   197
#define C_   768
#define H_   12
#define D_   64
#define BN   12608      // B_*N_
#define BN_PAD 12672    // 99*128 (GEMM M padded)
#define QKV_ELEMS 9682944   // B_*H_*N_*D_ = BN*C_
#define SCALE 0.125f    // D^-0.5

typedef unsigned short ushort_t;
using bf16x8  = __attribute__((ext_vector_type(8))) __bf16;
using floatx4 = __attribute__((ext_vector_type(4))) float;

__device__ __forceinline__ ushort_t f2bf(float f) {
    union { float f; unsigned u; } v; v.f = f;
    unsigned r = v.u + 0x7FFF + ((v.u >> 16) & 1);   // RNE
    return (ushort_t)(r >> 16);
}

__device__ __forceinline__ void gload_lds16(const void* g, void* l) {
    __builtin_amdgcn_global_load_lds(
        (const __attribute__((address_space(1))) unsigned*)g,
        (__attribute__((address_space(3))) unsigned*)l, 16, 0, 0);
}

// ---------------------------------------------------------------------------
// fp32 -> bf16 conversion (grid-stride over float4 groups)
// ---------------------------------------------------------------------------
__global__ __launch_bounds__(256) void cvt_f32_bf16(
    const float* __restrict__ src, ushort_t* __restrict__ dst, int n4)
{
    int i = blockIdx.x * 256 + threadIdx.x;
    if (i < n4) {
        float4 v = ((const float4*)src)[i];
        ushort4 o;
        o.x = f2bf(v.x); o.y = f2bf(v.y); o.z = f2bf(v.z); o.w = f2bf(v.w);
        ((ushort4*)dst)[i] = o;
    }
}

// ---------------------------------------------------------------------------
// Kernel 1: QKV projection GEMM, bf16 MFMA.
// Y[m,o] = sum_k x[m,k]*w[o,k];  128x128 tile, BK=32, 4 waves (each 64x64 =
// 4x4 grid of 16x16x32 MFMA).  LDS staged via global_load_lds width=16 with
// XOR granule swizzle (conflict-free frag reads).  Epilogue: +bias, *SCALE
// for q, scatter fp32 to (3,B,H,N,D).
// ---------------------------------------------------------------------------
__global__ __launch_bounds__(256, 4) void qkv_gemm_mfma(
    const ushort_t* __restrict__ xb,   // [BN_PAD, 768] bf16
    const ushort_t* __restrict__ wb,   // [2304, 768] bf16
    const float* __restrict__ qb,
    const float* __restrict__ kb,
    const float* __restrict__ vb,
    float* __restrict__ qkv)           // 3 x [B,H,N,D] fp32
{
    __shared__ ushort_t lA[128 * 32];
    __shared__ ushort_t lB[128 * 32];
    const int t = threadIdx.x;
    const int w = t >> 6, lane = t & 63;
    const int quad = lane >> 4, li = lane & 15;
    const int wm = w >> 1, wn = w & 1;
    const int o0 = blockIdx.x * 128, m0 = blockIdx.y * 128;

    floatx4 acc[4][4];
#pragma unroll
    for (int i = 0; i < 4; ++i)
#pragma unroll
        for (int j = 0; j < 4; ++j) acc[i][j] = (floatx4)0.f;

    const int srow = lane >> 2;                 // row within 16-row chunk
    const int sg   = (lane & 3) ^ (srow & 3);   // swizzled global granule
    const int rdg  = (quad ^ (li & 3)) * 8;     // frag-read granule offset (elts)

    for (int kt = 0; kt < 24; ++kt) {
        const int k0 = kt * 32;
#pragma unroll
        for (int s = 0; s < 2; ++s) {
            const int rl = w * 32 + s * 16;     // local row base of chunk
            gload_lds16(xb + ((size_t)(m0 + rl + srow)) * 768 + k0 + sg * 8,
                        &lA[rl * 32]);
            gload_lds16(wb + ((size_t)(o0 + rl + srow)) * 768 + k0 + sg * 8,
                        &lB[rl * 32]);
        }
        __syncthreads();
        bf16x8 af[4], bfr[4];
#pragma unroll
        for (int mi = 0; mi < 4; ++mi)
            af[mi] = *(const bf16x8*)&lA[(wm * 64 + mi * 16 + li) * 32 + rdg];
#pragma unroll
        for (int ni = 0; ni < 4; ++ni)
            bfr[ni] = *(const bf16x8*)&lB[(wn * 64 + ni * 16 + li) * 32 + rdg];
#pragma unroll
        for (int mi = 0; mi < 4; ++mi)
#pragma unroll
            for (int ni = 0; ni < 4; ++ni)
                acc[mi][ni] = __builtin_amdgcn_mfma_f32_16x16x32_bf16(
                    af[mi], bfr[ni], acc[mi][ni], 0, 0, 0);
        __syncthreads();
    }

    // epilogue: C/D layout col=li, row=quad*4+reg
    const int which = o0 / 768;
    const float* bias = (which == 0) ? qb : ((which == 1) ? kb : vb);
    float* dst = qkv + (size_t)which * QKV_ELEMS;
    const float sc = (which == 0) ? SCALE : 1.0f;

#pragma unroll
    for (int mi = 0; mi < 4; ++mi) {
#pragma unroll
        for (int r = 0; r < 4; ++r) {
            const int m = m0 + wm * 64 + mi * 16 + quad * 4 + r;
            if (m < BN) {
                const int b = m / 197, n = m % 197;
#pragma unroll
                for (int ni = 0; ni < 4; ++ni) {
                    const int o  = o0 + wn * 64 + ni * 16 + li;
                    const int ol = o - which * 768;
                    const int h = ol >> 6, d = ol & 63;
                    dst[(((size_t)b * 12 + h) * 197 + n) * 64 + d] =
                        (acc[mi][ni][r] + bias[ol]) * sc;
                }
            }
        }
    }
}

// ---------------------------------------------------------------------------
// Kernel 2: fused attention per (b,h) — unchanged fp32 math (R2, passed),
// except the output is now written as bf16 for the MFMA proj GEMM.
// ---------------------------------------------------------------------------
__global__ __launch_bounds__(256, 4) void attn_kernel(
    const float* __restrict__ qkv,        // ws base (Q,K,V)
    const float* __restrict__ rel_table,  // [732, 12]
    ushort_t* __restrict__ aout)          // [BN, 768] bf16
{
    __shared__ float Qs[64][68];   // [d][r]
    __shared__ float KV[64][68];   // K: [d][c]; later V: [c][d]
    __shared__ float P [64][68];   // [c][r]

    const int rt = blockIdx.x;     // 0..3 row tile
    const int bh = blockIdx.y;     // 0..767
    const int h  = bh % 12;
    const int bb = bh / 12;
    const size_t base = (size_t)bh * (197 * 64);
    const float* Q = qkv + base;
    const float* K = qkv + (size_t)QKV_ELEMS + base;
    const float* V = qkv + (size_t)2 * QKV_ELEMS + base;
    const int t = threadIdx.x, tx = t & 15, ty = t >> 4;
    const int r0 = rt * 64;

    {
        const int r = t >> 2, q = t & 3;
        const int n = r0 + r;
#pragma unroll
        for (int j = 0; j < 4; ++j) {
            const int d0 = q * 16 + j * 4;
            float4 v = (n < 197) ? *(const float4*)(Q + n * 64 + d0)
                                 : make_float4(0.f, 0.f, 0.f, 0.f);
            Qs[d0 + 0][r] = v.x; Qs[d0 + 1][r] = v.y;
            Qs[d0 + 2][r] = v.z; Qs[d0 + 3][r] = v.w;
        }
    }

    float m_run[4], l_run[4], accO[4][4];
#pragma unroll
    for (int i = 0; i < 4; ++i) {
        m_run[i] = -INFINITY; l_run[i] = 0.f;
#pragma unroll
        for (int j = 0; j < 4; ++j) accO[i][j] = 0.f;
    }

    for (int cc = 0; cc < 4; ++cc) {
        {
            const int c = t >> 2, q = t & 3;
            const int mg = cc * 64 + c;
#pragma unroll
            for (int j = 0; j < 4; ++j) {
                const int d0 = q * 16 + j * 4;
                float4 v = (mg < 197) ? *(const float4*)(K + mg * 64 + d0)
                                      : make_float4(0.f, 0.f, 0.f, 0.f);
                KV[d0 + 0][c] = v.x; KV[d0 + 1][c] = v.y;
                KV[d0 + 2][c] = v.z; KV[d0 + 3][c] = v.w;
            }
        }
        __syncthreads();

        float s[4][4];
#pragma unroll
        for (int i = 0; i < 4; ++i)
#pragma unroll
            for (int j = 0; j < 4; ++j) s[i][j] = 0.f;
#pragma unroll 8
        for (int d = 0; d < 64; ++d) {
            float a[4], b[4];
            *(float4*)a = *(const float4*)&Qs[d][ty * 4];
            *(float4*)b = *(const float4*)&KV[d][tx * 4];
#pragma unroll
            for (int i = 0; i < 4; ++i)
#pragma unroll
                for (int j = 0; j < 4; ++j)
                    s[i][j] = fmaf(a[i], b[j], s[i][j]);
        }

#pragma unroll
        for (int j = 0; j < 4; ++j) {
            const int mg = cc * 64 + tx * 4 + j;
            if (mg >= 197) {
#pragma unroll
                for (int i = 0; i < 4; ++i) s[i][j] = -1e30f;
            } else {
#pragma unroll
                for (int i = 0; i < 4; ++i) {
                    const int nr = r0 + ty * 4 + i;
                    const int n = (nr < 197) ? nr : 0;
                    int idx;
                    if (n == 0 && mg == 0)      idx = 731;
                    else if (n == 0)            idx = 729;
                    else if (mg == 0)           idx = 730;
                    else {
                        const int p = n - 1, q2 = mg - 1;
                        const int dr = (p / 14 - q2 / 14) + 13;
                        const int dc = (p % 14 - q2 % 14) + 13;
                        idx = dr * 27 + dc;
                    }
                    s[i][j] += rel_table[idx * 12 + h];
                }
            }
        }

#pragma unroll
        for (int i = 0; i < 4; ++i) {
            float mx = fmaxf(fmaxf(s[i][0], s[i][1]), fmaxf(s[i][2], s[i][3]));
#pragma unroll
            for (int off = 1; off < 16; off <<= 1)
                mx = fmaxf(mx, __shfl_xor(mx, off));
            const float mnew = fmaxf(m_run[i], mx);
            const float alpha = __expf(m_run[i] - mnew);
            m_run[i] = mnew;
            float rs = 0.f;
#pragma unroll
            for (int j = 0; j < 4; ++j) {
                s[i][j] = __expf(s[i][j] - mnew);
                rs += s[i][j];
            }
#pragma unroll
            for (int off = 1; off < 16; off <<= 1)
                rs += __shfl_xor(rs, off);
            l_run[i] = l_run[i] * alpha + rs;
#pragma unroll
            for (int j = 0; j < 4; ++j) accO[i][j] *= alpha;
        }

#pragma unroll
        for (int i = 0; i < 4; ++i)
#pragma unroll
            for (int j = 0; j < 4; ++j)
                P[tx * 4 + j][ty * 4 + i] = s[i][j];
        __syncthreads();

        {
            const int c = t >> 2, q = t & 3;
            const int mg = cc * 64 + c;
#pragma unroll
            for (int j = 0; j < 4; ++j) {
                const int d0 = q * 16 + j * 4;
                float4 v = (mg < 197) ? *(const float4*)(V + mg * 64 + d0)
                                      : make_float4(0.f, 0.f, 0.f, 0.f);
                *(float4*)&KV[c][d0] = v;
            }
        }
        __syncthreads();

#pragma unroll 8
        for (int c = 0; c < 64; ++c) {
            float a[4], b[4];
            *(float4*)a = *(const float4*)&P[c][ty * 4];
            *(float4*)b = *(const float4*)&KV[c][tx * 4];
#pragma unroll
            for (int i = 0; i < 4; ++i)
#pragma unroll
                for (int j = 0; j < 4; ++j)
                    accO[i][j] = fmaf(a[i], b[j], accO[i][j]);
        }
        __syncthreads();
    }

#pragma unroll
    for (int i = 0; i < 4; ++i) {
        const int n = r0 + ty * 4 + i;
        if (n < 197) {
            const float inv = 1.0f / l_run[i];
            ushort4 o;
            o.x = f2bf(accO[i][0] * inv);
            o.y = f2bf(accO[i][1] * inv);
            o.z = f2bf(accO[i][2] * inv);
            o.w = f2bf(accO[i][3] * inv);
            *(ushort4*)(aout + ((size_t)(bb * 197 + n)) * 768 + h * 64 + tx * 4) = o;
        }
    }
}

// ---------------------------------------------------------------------------
// Kernel 3: output projection GEMM, bf16 MFMA.  out[m,o] = sum a[m,k]*w[o,k]+b
// ---------------------------------------------------------------------------
__global__ __launch_bounds__(256, 4) void proj_gemm_mfma(
    const ushort_t* __restrict__ ab,   // [BN(_PAD), 768] bf16
    const ushort_t* __restrict__ wb,   // [768, 768] bf16
    const float* __restrict__ bias,    // [768]
    float* __restrict__ out)           // [BN, 768] fp32
{
    __shared__ ushort_t lA[128 * 32];
    __shared__ ushort_t lB[128 * 32];
    const int t = threadIdx.x;
    const int w = t >> 6, lane = t & 63;
    const int quad = lane >> 4, li = lane & 15;
    const int wm = w >> 1, wn = w & 1;
    const int o0 = blockIdx.x * 128, m0 = blockIdx.y * 128;

    floatx4 acc[4][4];
#pragma unroll
    for (int i = 0; i < 4; ++i)
#pragma unroll
        for (int j = 0; j < 4; ++j) acc[i][j] = (floatx4)0.f;

    const int srow = lane >> 2;
    const int sg   = (lane & 3) ^ (srow & 3);
    const int rdg  = (quad ^ (li & 3)) * 8;

    for (int kt = 0; kt < 24; ++kt) {
        const int k0 = kt * 32;
#pragma unroll
        for (int s = 0; s < 2; ++s) {
            const int rl = w * 32 + s * 16;
            gload_lds16(ab + ((size_t)(m0 + rl + srow)) * 768 + k0 + sg * 8,
                        &lA[rl * 32]);
            gload_lds16(wb + ((size_t)(o0 + rl + srow)) * 768 + k0 + sg * 8,
                        &lB[rl * 32]);
        }
        __syncthreads();
        bf16x8 af[4], bfr[4];
#pragma unroll
        for (int mi = 0; mi < 4; ++mi)
            af[mi] = *(const bf16x8*)&lA[(wm * 64 + mi * 16 + li) * 32 + rdg];
#pragma unroll
        for (int ni = 0; ni < 4; ++ni)
            bfr[ni] = *(const bf16x8*)&lB[(wn * 64 + ni * 16 + li) * 32 + rdg];
#pragma unroll
        for (int mi = 0; mi < 4; ++mi)
#pragma unroll
            for (int ni = 0; ni < 4; ++ni)
                acc[mi][ni] = __builtin_amdgcn_mfma_f32_16x16x32_bf16(
                    af[mi], bfr[ni], acc[mi][ni], 0, 0, 0);
        __syncthreads();
    }

#pragma unroll
    for (int mi = 0; mi < 4; ++mi) {
#pragma unroll
        for (int r = 0; r < 4; ++r) {
            const int m = m0 + wm * 64 + mi * 16 + quad * 4 + r;
            if (m < BN) {
                float* op = out + (size_t)m * 768;
#pragma unroll
                for (int ni = 0; ni < 4; ++ni) {
                    const int o = o0 + wn * 64 + ni * 16 + li;
                    op[o] = acc[mi][ni][r] + bias[o];
                }
            }
        }
    }
}

// ---------------------------------------------------------------------------
// ws layout (bytes):
//   [0, 116195328)              qkv fp32 (3 x B,H,N,D)
//   [116195328, 135659520)      xb bf16 [12672 x 768]; ALIASED by aout bf16
//                               [12608 x 768] after qkv_gemm consumed xb
//   [135659520, 139198464)      wb bf16 [2304 x 768]
//   [139198464, 140378112)      pwb bf16 [768 x 768]
// ---------------------------------------------------------------------------
extern "C" void kernel_launch(void* const* d_in, const int* in_sizes, int n_in,
                              void* d_out, int out_size, void* d_ws, size_t ws_size,
                              hipStream_t stream)
{
    const float* x         = (const float*)d_in[0];
    const float* qkv_w     = (const float*)d_in[1];
    const float* q_bias    = (const float*)d_in[2];
    const float* k_bias    = (const float*)d_in[3];
    const float* v_bias    = (const float*)d_in[4];
    const float* rel_table = (const float*)d_in[5];
    const float* proj_w    = (const float*)d_in[6];
    const float* proj_b    = (const float*)d_in[7];
    float* out = (float*)d_out;

    char* ws = (char*)d_ws;
    float*    qkv   = (float*)ws;
    ushort_t* xb    = (ushort_t*)(ws + 116195328);
    ushort_t* aoutb = xb;                      // alias (xb dead after qkv_gemm)
    ushort_t* wb    = (ushort_t*)(ws + 135659520);
    ushort_t* pwb   = (ushort_t*)(ws + 139198464);

    cvt_f32_bf16<<<(2420736 + 255) / 256, 256, 0, stream>>>(x, xb, 2420736);
    cvt_f32_bf16<<<(442368 + 255) / 256, 256, 0, stream>>>(qkv_w, wb, 442368);
    cvt_f32_bf16<<<(147456 + 255) / 256, 256, 0, stream>>>(proj_w, pwb, 147456);

    dim3 g1(18, 99);
    qkv_gemm_mfma<<<g1, 256, 0, stream>>>(xb, wb, q_bias, k_bias, v_bias, qkv);

    dim3 g2(4, 768);
    attn_kernel<<<g2, 256, 0, stream>>>(qkv, rel_table, aoutb);

    dim3 g3(6, 99);
    proj_gemm_mfma<<<g3, 256, 0, stream>>>(aoutb, pwb, proj_b, out);
}

// Round 4
// 257.057 us; speedup vs baseline: 33.4866x; 1.6595x over previous
//
#include <hip/hip_runtime.h>
#include <math.h>

#define B_   64
#define N_   197
#define C_   768
#define H_   12
#define D_   64
#define BN   12608      // B_*N_
#define BN_PAD 12672    // 99*128 (GEMM M padded)
#define QKV_ELEMS 9682944   // B_*H_*N_*D_ = BN*C_
#define SCALE 0.125f    // D^-0.5
#define STRV 80         // Vt/Ps LDS row stride (ushorts): 160B, 16B-aligned

typedef unsigned short ushort_t;
using bf16x8  = __attribute__((ext_vector_type(8))) __bf16;
using floatx4 = __attribute__((ext_vector_type(4))) float;
using ushort8 = __attribute__((ext_vector_type(8))) unsigned short;

__device__ __forceinline__ ushort_t f2bf(float f) {
    union { float f; unsigned u; } v; v.f = f;
    unsigned r = v.u + 0x7FFF + ((v.u >> 16) & 1);   // RNE
    return (ushort_t)(r >> 16);
}

__device__ __forceinline__ void gload_lds16(const void* g, void* l) {
    __builtin_amdgcn_global_load_lds(
        (const __attribute__((address_space(1))) unsigned*)g,
        (__attribute__((address_space(3))) unsigned*)l, 16, 0, 0);
}

// ---------------------------------------------------------------------------
// fp32 -> bf16 conversion
// ---------------------------------------------------------------------------
__global__ __launch_bounds__(256) void cvt_f32_bf16(
    const float* __restrict__ src, ushort_t* __restrict__ dst, int n4)
{
    int i = blockIdx.x * 256 + threadIdx.x;
    if (i < n4) {
        float4 v = ((const float4*)src)[i];
        ushort4 o;
        o.x = f2bf(v.x); o.y = f2bf(v.y); o.z = f2bf(v.z); o.w = f2bf(v.w);
        ((ushort4*)dst)[i] = o;
    }
}

// ---------------------------------------------------------------------------
// Kernel 1: QKV projection GEMM, bf16 MFMA.  Epilogue now writes bf16
// Q(scaled)/K/V in (B,H,N,D) layout for the MFMA attention kernel.
// ---------------------------------------------------------------------------
__global__ __launch_bounds__(256, 4) void qkv_gemm_mfma(
    const ushort_t* __restrict__ xb,   // [BN_PAD, 768] bf16
    const ushort_t* __restrict__ wb,   // [2304, 768] bf16
    const float* __restrict__ qb,
    const float* __restrict__ kb,
    const float* __restrict__ vb,
    ushort_t* __restrict__ qkvb)       // 3 x [B,H,N,D] bf16
{
    __shared__ ushort_t lA[128 * 32];
    __shared__ ushort_t lB[128 * 32];
    const int t = threadIdx.x;
    const int w = t >> 6, lane = t & 63;
    const int quad = lane >> 4, li = lane & 15;
    const int wm = w >> 1, wn = w & 1;
    const int o0 = blockIdx.x * 128, m0 = blockIdx.y * 128;

    floatx4 acc[4][4];
#pragma unroll
    for (int i = 0; i < 4; ++i)
#pragma unroll
        for (int j = 0; j < 4; ++j) acc[i][j] = (floatx4)0.f;

    const int srow = lane >> 2;
    const int sg   = (lane & 3) ^ (srow & 3);
    const int rdg  = (quad ^ (li & 3)) * 8;

    for (int kt = 0; kt < 24; ++kt) {
        const int k0 = kt * 32;
#pragma unroll
        for (int s = 0; s < 2; ++s) {
            const int rl = w * 32 + s * 16;
            gload_lds16(xb + ((size_t)(m0 + rl + srow)) * 768 + k0 + sg * 8,
                        &lA[rl * 32]);
            gload_lds16(wb + ((size_t)(o0 + rl + srow)) * 768 + k0 + sg * 8,
                        &lB[rl * 32]);
        }
        __syncthreads();
        bf16x8 af[4], bfr[4];
#pragma unroll
        for (int mi = 0; mi < 4; ++mi)
            af[mi] = *(const bf16x8*)&lA[(wm * 64 + mi * 16 + li) * 32 + rdg];
#pragma unroll
        for (int ni = 0; ni < 4; ++ni)
            bfr[ni] = *(const bf16x8*)&lB[(wn * 64 + ni * 16 + li) * 32 + rdg];
#pragma unroll
        for (int mi = 0; mi < 4; ++mi)
#pragma unroll
            for (int ni = 0; ni < 4; ++ni)
                acc[mi][ni] = __builtin_amdgcn_mfma_f32_16x16x32_bf16(
                    af[mi], bfr[ni], acc[mi][ni], 0, 0, 0);
        __syncthreads();
    }

    const int which = o0 / 768;
    const float* bias = (which == 0) ? qb : ((which == 1) ? kb : vb);
    ushort_t* dst = qkvb + (size_t)which * QKV_ELEMS;
    const float sc = (which == 0) ? SCALE : 1.0f;

#pragma unroll
    for (int mi = 0; mi < 4; ++mi) {
#pragma unroll
        for (int r = 0; r < 4; ++r) {
            const int m = m0 + wm * 64 + mi * 16 + quad * 4 + r;
            if (m < BN) {
                const int b = m / 197, n = m % 197;
#pragma unroll
                for (int ni = 0; ni < 4; ++ni) {
                    const int o  = o0 + wn * 64 + ni * 16 + li;
                    const int ol = o - which * 768;
                    const int h = ol >> 6, d = ol & 63;
                    dst[(((size_t)b * 12 + h) * 197 + n) * 64 + d] =
                        f2bf((acc[mi][ni][r] + bias[ol]) * sc);
                }
            }
        }
    }
}

// ---------------------------------------------------------------------------
// Kernel 2: fused MFMA attention.  Block = (row-tile rt of 64 Q rows) x (b,h).
// 4 waves, each owns 16 Q rows.  Online softmax in fp32; QK^T and PV on the
// matrix pipe (16x16x32 bf16 MFMA).  K/Q staged by global_load_lds with XOR
// granule swizzle; V transposed into LDS (stride 80); P round-trips through
// per-wave-private LDS (no extra barrier).
// ---------------------------------------------------------------------------
__global__ __launch_bounds__(256, 4) void attn_mfma(
    const ushort_t* __restrict__ qkvb,    // Qb,Kb,Vb consecutive, bf16
    const float* __restrict__ rel_table,  // [732, 12]
    ushort_t* __restrict__ aout)          // [BN, 768] bf16
{
    __shared__ ushort_t Qs[64 * 64];
    __shared__ ushort_t Ks[64 * 64];
    __shared__ ushort_t Vt[64 * STRV];
    __shared__ ushort_t Ps[64 * STRV];
    __shared__ float relh[732];

    const int rt = blockIdx.x, bh = blockIdx.y;
    const int h = bh % 12, bb = bh / 12;
    const int t = threadIdx.x;
    const int w = t >> 6, lane = t & 63, quad = lane >> 4, li = lane & 15;
    const size_t base = (size_t)bh * (197 * 64);
    const ushort_t* Qg = qkvb + base;
    const ushort_t* Kg = qkvb + (size_t)QKV_ELEMS + base;
    const ushort_t* Vg = qkvb + (size_t)2 * QKV_ELEMS + base;
    const int r0 = rt * 64;

    // stage this head's rel-table column
    for (int i = t; i < 732; i += 256) relh[i] = rel_table[i * 12 + h];

    // stage Q tile (rows r0..r0+63) via swizzled DMA
    {
        const int rloc = lane >> 3, g = (lane & 7) ^ rloc;
#pragma unroll
        for (int s = 0; s < 2; ++s) {
            const int rb = (w * 2 + s) * 8;
            gload_lds16(Qg + (size_t)(r0 + rb + rloc) * 64 + g * 8, &Qs[rb * 64]);
        }
    }

    // per-row constants (row n = r0 + w*16 + quad*4 + r)
    int nrow[4], p14[4], pm[4];
#pragma unroll
    for (int r = 0; r < 4; ++r) {
        const int n = r0 + w * 16 + quad * 4 + r;
        nrow[r] = n;
        const int ne = (n < 197) ? n : 0;     // clamp for idx math only
        const int p = (ne > 0) ? ne - 1 : 0;
        p14[r] = p / 14; pm[r] = p % 14;
    }

    float m_run[4], l_run[4];
    floatx4 accO[4];
#pragma unroll
    for (int r = 0; r < 4; ++r) { m_run[r] = -INFINITY; l_run[r] = 0.f; }
#pragma unroll
    for (int dt = 0; dt < 4; ++dt) accO[dt] = (floatx4)0.f;

    __syncthreads();   // Q + relh ready

    // Q A-frags (constant across chunks)
    bf16x8 aq0, aq1;
    {
        const int rq = w * 16 + li, rx = rq & 7;
        aq0 = *(const bf16x8*)&Qs[rq * 64 + (quad ^ rx) * 8];
        aq1 = *(const bf16x8*)&Qs[rq * 64 + ((4 + quad) ^ rx) * 8];
    }

    for (int cc = 0; cc < 4; ++cc) {
        // ---- stage K chunk (swizzled DMA) ----
        {
            const int rloc = lane >> 3, g = (lane & 7) ^ rloc;
#pragma unroll
            for (int s = 0; s < 2; ++s) {
                const int rb = (w * 2 + s) * 8;
                gload_lds16(Kg + (size_t)(cc * 64 + rb + rloc) * 64 + g * 8,
                            &Ks[rb * 64]);
            }
        }
        // ---- stage V chunk transposed: Vt[d][c] ----
        {
            const int c = lane;            // t&63
            const int mg = cc * 64 + c;
            ushort8 v0, v1;
            if (mg < 197) {
                v0 = *(const ushort8*)(Vg + (size_t)mg * 64 + w * 16);
                v1 = *(const ushort8*)(Vg + (size_t)mg * 64 + w * 16 + 8);
            } else {
                v0 = (ushort8)(unsigned short)0; v1 = v0;
            }
#pragma unroll
            for (int j = 0; j < 8; ++j) Vt[(w * 16 + j) * STRV + c] = v0[j];
#pragma unroll
            for (int j = 0; j < 8; ++j) Vt[(w * 16 + 8 + j) * STRV + c] = v1[j];
        }
        __syncthreads();

        // ---- S = Q K^T : 4 col-tiles x (2 MFMAs over d) ----
        floatx4 sacc[4];
#pragma unroll
        for (int tl = 0; tl < 4; ++tl) {
            const int rk = tl * 16 + li, rx = rk & 7;
            bf16x8 bk0 = *(const bf16x8*)&Ks[rk * 64 + (quad ^ rx) * 8];
            bf16x8 bk1 = *(const bf16x8*)&Ks[rk * 64 + ((4 + quad) ^ rx) * 8];
            floatx4 sa = (floatx4)0.f;
            sa = __builtin_amdgcn_mfma_f32_16x16x32_bf16(aq0, bk0, sa, 0, 0, 0);
            sa = __builtin_amdgcn_mfma_f32_16x16x32_bf16(aq1, bk1, sa, 0, 0, 0);
            sacc[tl] = sa;
        }

        // ---- rel-pos bias + col mask ----
#pragma unroll
        for (int tl = 0; tl < 4; ++tl) {
            const int mg = cc * 64 + tl * 16 + li;
            if (mg >= 197) {
#pragma unroll
                for (int r = 0; r < 4; ++r) sacc[tl][r] = -INFINITY;
            } else {
                const int qq = (mg > 0) ? mg - 1 : 0;
                const int q14 = qq / 14, qm = qq % 14;
#pragma unroll
                for (int r = 0; r < 4; ++r) {
                    int idx;
                    const int n0 = (nrow[r] < 197) ? nrow[r] : 0;
                    if (n0 == 0 && mg == 0)      idx = 731;
                    else if (n0 == 0)            idx = 729;
                    else if (mg == 0)            idx = 730;
                    else idx = (p14[r] - q14 + 13) * 27 + (pm[r] - qm + 13);
                    sacc[tl][r] += relh[idx];
                }
            }
        }

        // ---- online softmax (fp32) + P -> LDS (bf16) ----
#pragma unroll
        for (int r = 0; r < 4; ++r) {
            float mx = fmaxf(fmaxf(sacc[0][r], sacc[1][r]),
                             fmaxf(sacc[2][r], sacc[3][r]));
            mx = fmaxf(mx, __shfl_xor(mx, 1));
            mx = fmaxf(mx, __shfl_xor(mx, 2));
            mx = fmaxf(mx, __shfl_xor(mx, 4));
            mx = fmaxf(mx, __shfl_xor(mx, 8));
            const float mnew = fmaxf(m_run[r], mx);
            const float alpha = __expf(m_run[r] - mnew);
            m_run[r] = mnew;
            const float p0 = __expf(sacc[0][r] - mnew);
            const float p1 = __expf(sacc[1][r] - mnew);
            const float p2 = __expf(sacc[2][r] - mnew);
            const float p3 = __expf(sacc[3][r] - mnew);
            float rs = p0 + p1 + p2 + p3;
            rs += __shfl_xor(rs, 1);
            rs += __shfl_xor(rs, 2);
            rs += __shfl_xor(rs, 4);
            rs += __shfl_xor(rs, 8);
            l_run[r] = l_run[r] * alpha + rs;
#pragma unroll
            for (int dt = 0; dt < 4; ++dt) accO[dt][r] *= alpha;
            const int prow = w * 16 + quad * 4 + r;
            Ps[prow * STRV +  0 + li] = f2bf(p0);
            Ps[prow * STRV + 16 + li] = f2bf(p1);
            Ps[prow * STRV + 32 + li] = f2bf(p2);
            Ps[prow * STRV + 48 + li] = f2bf(p3);
        }

        // ---- O += P V : per-wave-private P section, no barrier needed ----
        {
            const int rp = w * 16 + li;
            bf16x8 pa0 = *(const bf16x8*)&Ps[rp * STRV + 0  + quad * 8];
            bf16x8 pa1 = *(const bf16x8*)&Ps[rp * STRV + 32 + quad * 8];
#pragma unroll
            for (int dt = 0; dt < 4; ++dt) {
                const int rv = dt * 16 + li;
                bf16x8 bv0 = *(const bf16x8*)&Vt[rv * STRV + 0  + quad * 8];
                bf16x8 bv1 = *(const bf16x8*)&Vt[rv * STRV + 32 + quad * 8];
                accO[dt] = __builtin_amdgcn_mfma_f32_16x16x32_bf16(
                    pa0, bv0, accO[dt], 0, 0, 0);
                accO[dt] = __builtin_amdgcn_mfma_f32_16x16x32_bf16(
                    pa1, bv1, accO[dt], 0, 0, 0);
            }
        }
        __syncthreads();
    }

    // ---- finalize: /l, store bf16 to (B,N,C) ----
#pragma unroll
    for (int r = 0; r < 4; ++r) {
        const int n = nrow[r];
        if (n < 197) {
            const float inv = 1.0f / l_run[r];
            ushort_t* op = aout + ((size_t)(bb * 197 + n)) * 768 + h * 64;
#pragma unroll
            for (int dt = 0; dt < 4; ++dt)
                op[dt * 16 + li] = f2bf(accO[dt][r] * inv);
        }
    }
}

// ---------------------------------------------------------------------------
// Kernel 3: output projection GEMM, bf16 MFMA.
// ---------------------------------------------------------------------------
__global__ __launch_bounds__(256, 4) void proj_gemm_mfma(
    const ushort_t* __restrict__ ab,   // [BN_PAD, 768] bf16
    const ushort_t* __restrict__ wb,   // [768, 768] bf16
    const float* __restrict__ bias,    // [768]
    float* __restrict__ out)           // [BN, 768] fp32
{
    __shared__ ushort_t lA[128 * 32];
    __shared__ ushort_t lB[128 * 32];
    const int t = threadIdx.x;
    const int w = t >> 6, lane = t & 63;
    const int quad = lane >> 4, li = lane & 15;
    const int wm = w >> 1, wn = w & 1;
    const int o0 = blockIdx.x * 128, m0 = blockIdx.y * 128;

    floatx4 acc[4][4];
#pragma unroll
    for (int i = 0; i < 4; ++i)
#pragma unroll
        for (int j = 0; j < 4; ++j) acc[i][j] = (floatx4)0.f;

    const int srow = lane >> 2;
    const int sg   = (lane & 3) ^ (srow & 3);
    const int rdg  = (quad ^ (li & 3)) * 8;

    for (int kt = 0; kt < 24; ++kt) {
        const int k0 = kt * 32;
#pragma unroll
        for (int s = 0; s < 2; ++s) {
            const int rl = w * 32 + s * 16;
            gload_lds16(ab + ((size_t)(m0 + rl + srow)) * 768 + k0 + sg * 8,
                        &lA[rl * 32]);
            gload_lds16(wb + ((size_t)(o0 + rl + srow)) * 768 + k0 + sg * 8,
                        &lB[rl * 32]);
        }
        __syncthreads();
        bf16x8 af[4], bfr[4];
#pragma unroll
        for (int mi = 0; mi < 4; ++mi)
            af[mi] = *(const bf16x8*)&lA[(wm * 64 + mi * 16 + li) * 32 + rdg];
#pragma unroll
        for (int ni = 0; ni < 4; ++ni)
            bfr[ni] = *(const bf16x8*)&lB[(wn * 64 + ni * 16 + li) * 32 + rdg];
#pragma unroll
        for (int mi = 0; mi < 4; ++mi)
#pragma unroll
            for (int ni = 0; ni < 4; ++ni)
                acc[mi][ni] = __builtin_amdgcn_mfma_f32_16x16x32_bf16(
                    af[mi], bfr[ni], acc[mi][ni], 0, 0, 0);
        __syncthreads();
    }

#pragma unroll
    for (int mi = 0; mi < 4; ++mi) {
#pragma unroll
        for (int r = 0; r < 4; ++r) {
            const int m = m0 + wm * 64 + mi * 16 + quad * 4 + r;
            if (m < BN) {
                float* op = out + (size_t)m * 768;
#pragma unroll
                for (int ni = 0; ni < 4; ++ni) {
                    const int o = o0 + wn * 64 + ni * 16 + li;
                    op[o] = acc[mi][ni][r] + bias[o];
                }
            }
        }
    }
}

// ---------------------------------------------------------------------------
// ws layout (bytes):
//   [0, 58097664)            qkvb bf16 (3 x B,H,N,D)
//   [58097664, 77561856)     xb bf16 [12672 x 768]; aliased by aout bf16
//   [77561856, 81100800)     wb bf16 [2304 x 768]
//   [81100800, 82280448)     pwb bf16 [768 x 768]
// ---------------------------------------------------------------------------
extern "C" void kernel_launch(void* const* d_in, const int* in_sizes, int n_in,
                              void* d_out, int out_size, void* d_ws, size_t ws_size,
                              hipStream_t stream)
{
    const float* x         = (const float*)d_in[0];
    const float* qkv_w     = (const float*)d_in[1];
    const float* q_bias    = (const float*)d_in[2];
    const float* k_bias    = (const float*)d_in[3];
    const float* v_bias    = (const float*)d_in[4];
    const float* rel_table = (const float*)d_in[5];
    const float* proj_w    = (const float*)d_in[6];
    const float* proj_b    = (const float*)d_in[7];
    float* out = (float*)d_out;

    char* ws = (char*)d_ws;
    ushort_t* qkvb  = (ushort_t*)ws;
    ushort_t* xb    = (ushort_t*)(ws + 58097664);
    ushort_t* aoutb = xb;                      // alias (xb dead after qkv_gemm)
    ushort_t* wb    = (ushort_t*)(ws + 77561856);
    ushort_t* pwb   = (ushort_t*)(ws + 81100800);

    cvt_f32_bf16<<<(2420736 + 255) / 256, 256, 0, stream>>>(x, xb, 2420736);
    cvt_f32_bf16<<<(442368 + 255) / 256, 256, 0, stream>>>(qkv_w, wb, 442368);
    cvt_f32_bf16<<<(147456 + 255) / 256, 256, 0, stream>>>(proj_w, pwb, 147456);

    dim3 g1(18, 99);
    qkv_gemm_mfma<<<g1, 256, 0, stream>>>(xb, wb, q_bias, k_bias, v_bias, qkvb);

    dim3 g2(4, 768);
    attn_mfma<<<g2, 256, 0, stream>>>(qkvb, rel_table, aoutb);

    dim3 g3(6, 99);
    proj_gemm_mfma<<<g3, 256, 0, stream>>>(aoutb, pwb, proj_b, out);
}

// Round 5
// 240.323 us; speedup vs baseline: 35.8184x; 1.0696x over previous
//
#include <hip/hip_runtime.h>
#include <math.h>

#define B_   64
#define N_   197
#define C_   768
#define H_   12
#define D_   64
#define BN   12608      // B_*N_
#define BN_PAD 12672    // 99*128 (GEMM M padded)
#define QKV_ELEMS 9682944   // B_*H_*N_*D_ = BN*C_
#define SCALE 0.125f    // D^-0.5
#define STRV 80         // Vt/Ps LDS row stride (ushorts): 160B, 16B-aligned

typedef unsigned short ushort_t;
using bf16x8  = __attribute__((ext_vector_type(8))) __bf16;
using floatx4 = __attribute__((ext_vector_type(4))) float;
using ushort8 = __attribute__((ext_vector_type(8))) unsigned short;

__device__ __forceinline__ ushort_t f2bf(float f) {
    union { float f; unsigned u; } v; v.f = f;
    unsigned r = v.u + 0x7FFF + ((v.u >> 16) & 1);   // RNE
    return (ushort_t)(r >> 16);
}

__device__ __forceinline__ void gload_lds16(const void* g, void* l) {
    __builtin_amdgcn_global_load_lds(
        (const __attribute__((address_space(1))) unsigned*)g,
        (__attribute__((address_space(3))) unsigned*)l, 16, 0, 0);
}

// ---------------------------------------------------------------------------
// fp32 -> bf16 conversion
// ---------------------------------------------------------------------------
__global__ __launch_bounds__(256) void cvt_f32_bf16(
    const float* __restrict__ src, ushort_t* __restrict__ dst, int n4)
{
    int i = blockIdx.x * 256 + threadIdx.x;
    if (i < n4) {
        float4 v = ((const float4*)src)[i];
        ushort4 o;
        o.x = f2bf(v.x); o.y = f2bf(v.y); o.z = f2bf(v.z); o.w = f2bf(v.w);
        ((ushort4*)dst)[i] = o;
    }
}

// ---------------------------------------------------------------------------
// Kernel 1: QKV projection GEMM, bf16 MFMA, BK=64 (R4: 12 K-iters instead of
// 24 -> half the vmcnt(0)+barrier drains; 32 MFMAs per barrier pair).
// 128x128 tile, 4 waves each 64x64.  8-granule XOR swizzle: DMA lane (rloc=
// lane>>3, gl=lane&7) fetches global granule gl^rloc, so LDS granule g of row
// r holds global granule g^(r&7); frag reads un-swizzle with ^(li&7).
// Epilogue writes bf16 Q(scaled)/K/V in (B,H,N,D).
// ---------------------------------------------------------------------------
__global__ __launch_bounds__(256, 4) void qkv_gemm_mfma(
    const ushort_t* __restrict__ xb,   // [BN_PAD, 768] bf16
    const ushort_t* __restrict__ wb,   // [2304, 768] bf16
    const float* __restrict__ qb,
    const float* __restrict__ kb,
    const float* __restrict__ vb,
    ushort_t* __restrict__ qkvb)       // 3 x [B,H,N,D] bf16
{
    __shared__ ushort_t lA[128 * 64];
    __shared__ ushort_t lB[128 * 64];
    const int t = threadIdx.x;
    const int w = t >> 6, lane = t & 63;
    const int quad = lane >> 4, li = lane & 15;
    const int wm = w >> 1, wn = w & 1;
    const int o0 = blockIdx.x * 128, m0 = blockIdx.y * 128;

    floatx4 acc[4][4];
#pragma unroll
    for (int i = 0; i < 4; ++i)
#pragma unroll
        for (int j = 0; j < 4; ++j) acc[i][j] = (floatx4)0.f;

    const int rloc = lane >> 3;            // row within 8-row DMA chunk
    const int gdma = (lane & 7) ^ rloc;    // swizzled global granule
    const int rx   = li & 7;               // frag-read un-swizzle key

    for (int kt = 0; kt < 12; ++kt) {
        const int k0 = kt * 64;
#pragma unroll
        for (int s = 0; s < 4; ++s) {
            const int rb = w * 32 + s * 8;
            gload_lds16(xb + ((size_t)(m0 + rb + rloc)) * 768 + k0 + gdma * 8,
                        &lA[rb * 64]);
            gload_lds16(wb + ((size_t)(o0 + rb + rloc)) * 768 + k0 + gdma * 8,
                        &lB[rb * 64]);
        }
        __syncthreads();
#pragma unroll
        for (int kk = 0; kk < 2; ++kk) {
            bf16x8 af[4], bfr[4];
#pragma unroll
            for (int mi = 0; mi < 4; ++mi)
                af[mi] = *(const bf16x8*)
                    &lA[(wm * 64 + mi * 16 + li) * 64 + ((kk * 4 + quad) ^ rx) * 8];
#pragma unroll
            for (int ni = 0; ni < 4; ++ni)
                bfr[ni] = *(const bf16x8*)
                    &lB[(wn * 64 + ni * 16 + li) * 64 + ((kk * 4 + quad) ^ rx) * 8];
#pragma unroll
            for (int mi = 0; mi < 4; ++mi)
#pragma unroll
                for (int ni = 0; ni < 4; ++ni)
                    acc[mi][ni] = __builtin_amdgcn_mfma_f32_16x16x32_bf16(
                        af[mi], bfr[ni], acc[mi][ni], 0, 0, 0);
        }
        __syncthreads();
    }

    const int which = o0 / 768;
    const float* bias = (which == 0) ? qb : ((which == 1) ? kb : vb);
    ushort_t* dst = qkvb + (size_t)which * QKV_ELEMS;
    const float sc = (which == 0) ? SCALE : 1.0f;

#pragma unroll
    for (int mi = 0; mi < 4; ++mi) {
#pragma unroll
        for (int r = 0; r < 4; ++r) {
            const int m = m0 + wm * 64 + mi * 16 + quad * 4 + r;
            if (m < BN) {
                const int b = m / 197, n = m % 197;
#pragma unroll
                for (int ni = 0; ni < 4; ++ni) {
                    const int o  = o0 + wn * 64 + ni * 16 + li;
                    const int ol = o - which * 768;
                    const int h = ol >> 6, d = ol & 63;
                    dst[(((size_t)b * 12 + h) * 197 + n) * 64 + d] =
                        f2bf((acc[mi][ni][r] + bias[ol]) * sc);
                }
            }
        }
    }
}

// ---------------------------------------------------------------------------
// Kernel 2: fused MFMA attention (unchanged from R4 — passed at ~80 us).
// ---------------------------------------------------------------------------
__global__ __launch_bounds__(256, 4) void attn_mfma(
    const ushort_t* __restrict__ qkvb,    // Qb,Kb,Vb consecutive, bf16
    const float* __restrict__ rel_table,  // [732, 12]
    ushort_t* __restrict__ aout)          // [BN, 768] bf16
{
    __shared__ ushort_t Qs[64 * 64];
    __shared__ ushort_t Ks[64 * 64];
    __shared__ ushort_t Vt[64 * STRV];
    __shared__ ushort_t Ps[64 * STRV];
    __shared__ float relh[732];

    const int rt = blockIdx.x, bh = blockIdx.y;
    const int h = bh % 12, bb = bh / 12;
    const int t = threadIdx.x;
    const int w = t >> 6, lane = t & 63, quad = lane >> 4, li = lane & 15;
    const size_t base = (size_t)bh * (197 * 64);
    const ushort_t* Qg = qkvb + base;
    const ushort_t* Kg = qkvb + (size_t)QKV_ELEMS + base;
    const ushort_t* Vg = qkvb + (size_t)2 * QKV_ELEMS + base;
    const int r0 = rt * 64;

    for (int i = t; i < 732; i += 256) relh[i] = rel_table[i * 12 + h];

    {
        const int rloc = lane >> 3, g = (lane & 7) ^ rloc;
#pragma unroll
        for (int s = 0; s < 2; ++s) {
            const int rb = (w * 2 + s) * 8;
            gload_lds16(Qg + (size_t)(r0 + rb + rloc) * 64 + g * 8, &Qs[rb * 64]);
        }
    }

    int nrow[4], p14[4], pm[4];
#pragma unroll
    for (int r = 0; r < 4; ++r) {
        const int n = r0 + w * 16 + quad * 4 + r;
        nrow[r] = n;
        const int ne = (n < 197) ? n : 0;
        const int p = (ne > 0) ? ne - 1 : 0;
        p14[r] = p / 14; pm[r] = p % 14;
    }

    float m_run[4], l_run[4];
    floatx4 accO[4];
#pragma unroll
    for (int r = 0; r < 4; ++r) { m_run[r] = -INFINITY; l_run[r] = 0.f; }
#pragma unroll
    for (int dt = 0; dt < 4; ++dt) accO[dt] = (floatx4)0.f;

    __syncthreads();

    bf16x8 aq0, aq1;
    {
        const int rq = w * 16 + li, rxq = rq & 7;
        aq0 = *(const bf16x8*)&Qs[rq * 64 + (quad ^ rxq) * 8];
        aq1 = *(const bf16x8*)&Qs[rq * 64 + ((4 + quad) ^ rxq) * 8];
    }

    for (int cc = 0; cc < 4; ++cc) {
        {
            const int rloc = lane >> 3, g = (lane & 7) ^ rloc;
#pragma unroll
            for (int s = 0; s < 2; ++s) {
                const int rb = (w * 2 + s) * 8;
                gload_lds16(Kg + (size_t)(cc * 64 + rb + rloc) * 64 + g * 8,
                            &Ks[rb * 64]);
            }
        }
        {
            const int c = lane;
            const int mg = cc * 64 + c;
            ushort8 v0, v1;
            if (mg < 197) {
                v0 = *(const ushort8*)(Vg + (size_t)mg * 64 + w * 16);
                v1 = *(const ushort8*)(Vg + (size_t)mg * 64 + w * 16 + 8);
            } else {
                v0 = (ushort8)(unsigned short)0; v1 = v0;
            }
#pragma unroll
            for (int j = 0; j < 8; ++j) Vt[(w * 16 + j) * STRV + c] = v0[j];
#pragma unroll
            for (int j = 0; j < 8; ++j) Vt[(w * 16 + 8 + j) * STRV + c] = v1[j];
        }
        __syncthreads();

        floatx4 sacc[4];
#pragma unroll
        for (int tl = 0; tl < 4; ++tl) {
            const int rk = tl * 16 + li, rxk = rk & 7;
            bf16x8 bk0 = *(const bf16x8*)&Ks[rk * 64 + (quad ^ rxk) * 8];
            bf16x8 bk1 = *(const bf16x8*)&Ks[rk * 64 + ((4 + quad) ^ rxk) * 8];
            floatx4 sa = (floatx4)0.f;
            sa = __builtin_amdgcn_mfma_f32_16x16x32_bf16(aq0, bk0, sa, 0, 0, 0);
            sa = __builtin_amdgcn_mfma_f32_16x16x32_bf16(aq1, bk1, sa, 0, 0, 0);
            sacc[tl] = sa;
        }

#pragma unroll
        for (int tl = 0; tl < 4; ++tl) {
            const int mg = cc * 64 + tl * 16 + li;
            if (mg >= 197) {
#pragma unroll
                for (int r = 0; r < 4; ++r) sacc[tl][r] = -INFINITY;
            } else {
                const int qq = (mg > 0) ? mg - 1 : 0;
                const int q14 = qq / 14, qm = qq % 14;
#pragma unroll
                for (int r = 0; r < 4; ++r) {
                    int idx;
                    const int n0 = (nrow[r] < 197) ? nrow[r] : 0;
                    if (n0 == 0 && mg == 0)      idx = 731;
                    else if (n0 == 0)            idx = 729;
                    else if (mg == 0)            idx = 730;
                    else idx = (p14[r] - q14 + 13) * 27 + (pm[r] - qm + 13);
                    sacc[tl][r] += relh[idx];
                }
            }
        }

#pragma unroll
        for (int r = 0; r < 4; ++r) {
            float mx = fmaxf(fmaxf(sacc[0][r], sacc[1][r]),
                             fmaxf(sacc[2][r], sacc[3][r]));
            mx = fmaxf(mx, __shfl_xor(mx, 1));
            mx = fmaxf(mx, __shfl_xor(mx, 2));
            mx = fmaxf(mx, __shfl_xor(mx, 4));
            mx = fmaxf(mx, __shfl_xor(mx, 8));
            const float mnew = fmaxf(m_run[r], mx);
            const float alpha = __expf(m_run[r] - mnew);
            m_run[r] = mnew;
            const float p0 = __expf(sacc[0][r] - mnew);
            const float p1 = __expf(sacc[1][r] - mnew);
            const float p2 = __expf(sacc[2][r] - mnew);
            const float p3 = __expf(sacc[3][r] - mnew);
            float rs = p0 + p1 + p2 + p3;
            rs += __shfl_xor(rs, 1);
            rs += __shfl_xor(rs, 2);
            rs += __shfl_xor(rs, 4);
            rs += __shfl_xor(rs, 8);
            l_run[r] = l_run[r] * alpha + rs;
#pragma unroll
            for (int dt = 0; dt < 4; ++dt) accO[dt][r] *= alpha;
            const int prow = w * 16 + quad * 4 + r;
            Ps[prow * STRV +  0 + li] = f2bf(p0);
            Ps[prow * STRV + 16 + li] = f2bf(p1);
            Ps[prow * STRV + 32 + li] = f2bf(p2);
            Ps[prow * STRV + 48 + li] = f2bf(p3);
        }

        {
            const int rp = w * 16 + li;
            bf16x8 pa0 = *(const bf16x8*)&Ps[rp * STRV + 0  + quad * 8];
            bf16x8 pa1 = *(const bf16x8*)&Ps[rp * STRV + 32 + quad * 8];
#pragma unroll
            for (int dt = 0; dt < 4; ++dt) {
                const int rv = dt * 16 + li;
                bf16x8 bv0 = *(const bf16x8*)&Vt[rv * STRV + 0  + quad * 8];
                bf16x8 bv1 = *(const bf16x8*)&Vt[rv * STRV + 32 + quad * 8];
                accO[dt] = __builtin_amdgcn_mfma_f32_16x16x32_bf16(
                    pa0, bv0, accO[dt], 0, 0, 0);
                accO[dt] = __builtin_amdgcn_mfma_f32_16x16x32_bf16(
                    pa1, bv1, accO[dt], 0, 0, 0);
            }
        }
        __syncthreads();
    }

#pragma unroll
    for (int r = 0; r < 4; ++r) {
        const int n = nrow[r];
        if (n < 197) {
            const float inv = 1.0f / l_run[r];
            ushort_t* op = aout + ((size_t)(bb * 197 + n)) * 768 + h * 64;
#pragma unroll
            for (int dt = 0; dt < 4; ++dt)
                op[dt * 16 + li] = f2bf(accO[dt][r] * inv);
        }
    }
}

// ---------------------------------------------------------------------------
// Kernel 3: output projection GEMM, bf16 MFMA, BK=64 (same structure as K1).
// ---------------------------------------------------------------------------
__global__ __launch_bounds__(256, 4) void proj_gemm_mfma(
    const ushort_t* __restrict__ ab,   // [BN_PAD, 768] bf16
    const ushort_t* __restrict__ wb,   // [768, 768] bf16
    const float* __restrict__ bias,    // [768]
    float* __restrict__ out)           // [BN, 768] fp32
{
    __shared__ ushort_t lA[128 * 64];
    __shared__ ushort_t lB[128 * 64];
    const int t = threadIdx.x;
    const int w = t >> 6, lane = t & 63;
    const int quad = lane >> 4, li = lane & 15;
    const int wm = w >> 1, wn = w & 1;
    const int o0 = blockIdx.x * 128, m0 = blockIdx.y * 128;

    floatx4 acc[4][4];
#pragma unroll
    for (int i = 0; i < 4; ++i)
#pragma unroll
        for (int j = 0; j < 4; ++j) acc[i][j] = (floatx4)0.f;

    const int rloc = lane >> 3;
    const int gdma = (lane & 7) ^ rloc;
    const int rx   = li & 7;

    for (int kt = 0; kt < 12; ++kt) {
        const int k0 = kt * 64;
#pragma unroll
        for (int s = 0; s < 4; ++s) {
            const int rb = w * 32 + s * 8;
            gload_lds16(ab + ((size_t)(m0 + rb + rloc)) * 768 + k0 + gdma * 8,
                        &lA[rb * 64]);
            gload_lds16(wb + ((size_t)(o0 + rb + rloc)) * 768 + k0 + gdma * 8,
                        &lB[rb * 64]);
        }
        __syncthreads();
#pragma unroll
        for (int kk = 0; kk < 2; ++kk) {
            bf16x8 af[4], bfr[4];
#pragma unroll
            for (int mi = 0; mi < 4; ++mi)
                af[mi] = *(const bf16x8*)
                    &lA[(wm * 64 + mi * 16 + li) * 64 + ((kk * 4 + quad) ^ rx) * 8];
#pragma unroll
            for (int ni = 0; ni < 4; ++ni)
                bfr[ni] = *(const bf16x8*)
                    &lB[(wn * 64 + ni * 16 + li) * 64 + ((kk * 4 + quad) ^ rx) * 8];
#pragma unroll
            for (int mi = 0; mi < 4; ++mi)
#pragma unroll
                for (int ni = 0; ni < 4; ++ni)
                    acc[mi][ni] = __builtin_amdgcn_mfma_f32_16x16x32_bf16(
                        af[mi], bfr[ni], acc[mi][ni], 0, 0, 0);
        }
        __syncthreads();
    }

#pragma unroll
    for (int mi = 0; mi < 4; ++mi) {
#pragma unroll
        for (int r = 0; r < 4; ++r) {
            const int m = m0 + wm * 64 + mi * 16 + quad * 4 + r;
            if (m < BN) {
                float* op = out + (size_t)m * 768;
#pragma unroll
                for (int ni = 0; ni < 4; ++ni) {
                    const int o = o0 + wn * 64 + ni * 16 + li;
                    op[o] = acc[mi][ni][r] + bias[o];
                }
            }
        }
    }
}

// ---------------------------------------------------------------------------
// ws layout (bytes):
//   [0, 58097664)            qkvb bf16 (3 x B,H,N,D)
//   [58097664, 77561856)     xb bf16 [12672 x 768]; aliased by aout bf16
//   [77561856, 81100800)     wb bf16 [2304 x 768]
//   [81100800, 82280448)     pwb bf16 [768 x 768]
// ---------------------------------------------------------------------------
extern "C" void kernel_launch(void* const* d_in, const int* in_sizes, int n_in,
                              void* d_out, int out_size, void* d_ws, size_t ws_size,
                              hipStream_t stream)
{
    const float* x         = (const float*)d_in[0];
    const float* qkv_w     = (const float*)d_in[1];
    const float* q_bias    = (const float*)d_in[2];
    const float* k_bias    = (const float*)d_in[3];
    const float* v_bias    = (const float*)d_in[4];
    const float* rel_table = (const float*)d_in[5];
    const float* proj_w    = (const float*)d_in[6];
    const float* proj_b    = (const float*)d_in[7];
    float* out = (float*)d_out;

    char* ws = (char*)d_ws;
    ushort_t* qkvb  = (ushort_t*)ws;
    ushort_t* xb    = (ushort_t*)(ws + 58097664);
    ushort_t* aoutb = xb;                      // alias (xb dead after qkv_gemm)
    ushort_t* wb    = (ushort_t*)(ws + 77561856);
    ushort_t* pwb   = (ushort_t*)(ws + 81100800);

    cvt_f32_bf16<<<(2420736 + 255) / 256, 256, 0, stream>>>(x, xb, 2420736);
    cvt_f32_bf16<<<(442368 + 255) / 256, 256, 0, stream>>>(qkv_w, wb, 442368);
    cvt_f32_bf16<<<(147456 + 255) / 256, 256, 0, stream>>>(proj_w, pwb, 147456);

    dim3 g1(18, 99);
    qkv_gemm_mfma<<<g1, 256, 0, stream>>>(xb, wb, q_bias, k_bias, v_bias, qkvb);

    dim3 g2(4, 768);
    attn_mfma<<<g2, 256, 0, stream>>>(qkvb, rel_table, aoutb);

    dim3 g3(6, 99);
    proj_gemm_mfma<<<g3, 256, 0, stream>>>(aoutb, pwb, proj_b, out);
}